// Round 5
// baseline (616.387 us; speedup 1.0000x reference)
//
#include <hip/hip_runtime.h>

#define IGNORE_INDEX (-100)

constexpr int N_ROWS = 2048;
constexpr int D_DIM  = 1024;
constexpr int V_DIM  = 131072;
constexpr int BM = 256, BN = 256, BK = 128;
constexpr int ROW_TILES = N_ROWS / BM;        // 8
constexpr int COL_TILES = V_DIM / BN;         // 512
constexpr int NBLK = ROW_TILES * COL_TILES;   // 4096
constexpr int K_TILES = D_DIM / BK;           // 8

typedef __attribute__((ext_vector_type(4))) float f32x4;
typedef __attribute__((ext_vector_type(4))) int   i32x4;
typedef __attribute__((ext_vector_type(8))) int   i32x8;

// E8M0 scale 121 = 2^-6 in every byte: uniform -> lane/byte-select layout-proof.
#define SCL 0x79797979
#define PRESCALE 64.0f

// ---------------- f32 -> fp8 e4m3 (x64 pre-scale), 16 elems/thread ----------
__global__ __launch_bounds__(256)
void cvt_fp8(const float* __restrict__ src, unsigned char* __restrict__ dst) {
  const size_t i = ((size_t)blockIdx.x * 256 + (size_t)threadIdx.x) * 16;
  i32x4 o;
#pragma unroll
  for (int q = 0; q < 4; ++q) {
    const float4 f = *(const float4*)&src[i + q * 4];
    int w = 0;
    w = __builtin_amdgcn_cvt_pk_fp8_f32(f.x * PRESCALE, f.y * PRESCALE, w, false);
    w = __builtin_amdgcn_cvt_pk_fp8_f32(f.z * PRESCALE, f.w * PRESCALE, w, true);
    o[q] = w;
  }
  *(i32x4*)&dst[i] = o;
}

// ---------------- 256x256 MX-fp8 GEMM + partial row exp-sum ----------------
// A (hidden) staged in LDS (shared x4 by wn-waves), granule-permuted so reads
// use the round-3-proven conflict-free pattern. B (weight) loaded straight
// from global into registers (wave-private; L2/LLC-resident). One barrier
// per K-tile; counted vmcnt(8) drains exactly the A-DMA of the current tile.
#define BAR() __builtin_amdgcn_s_barrier()
#define SP1() __builtin_amdgcn_s_setprio(1)
#define SP0() __builtin_amdgcn_s_setprio(0)
#define SCHB() __builtin_amdgcn_sched_barrier(0)
#define VM8() asm volatile("s_waitcnt vmcnt(8)" ::: "memory")

// stage one 256x128 fp8 A-tile: 4 x global_load_lds(16B)/thread
#define STAGE_A(kt, buf)                                                       \
  {                                                                            \
    _Pragma("unroll") for (int j2_ = 0; j2_ < 4; ++j2_) {                      \
      const char* g_ = habase + (size_t)(j2_ * 64) * 1024 + (size_t)(kt) * 128;\
      __builtin_amdgcn_global_load_lds(                                        \
          (const __attribute__((address_space(1))) unsigned int*)g_,           \
          (__attribute__((address_space(3))) unsigned int*)(smem +             \
              (buf) * 32768 + j2_ * 8192 + (w << 10)),                         \
          16, 0, 0);                                                           \
    }                                                                          \
  }

// read 4 A-frags (one mq) from LDS; offsets = proven (g*16 / 64+g*16) ^ swz
#define READ_A(mq, buf)                                                        \
  _Pragma("unroll") for (int mf_ = 0; mf_ < 4; ++mf_) {                        \
    const char* p_ = smem + (buf) * 32768 +                                    \
        (wm * 128 + (mq) * 64 + mf_ * 16 + l15) * 128;                         \
    const i32x4 lo_ = *(const i32x4*)(p_ + ((l16g * 16) ^ swz));               \
    const i32x4 hi_ = *(const i32x4*)(p_ + ((64 + l16g * 16) ^ swz));          \
    areg[mf_] = (i32x8){lo_[0], lo_[1], lo_[2], lo_[3],                        \
                        hi_[0], hi_[1], hi_[2], hi_[3]};                       \
  }

// load 4 B-frags (whole wave-column, one K-tile) global -> regs
#define LOAD_B(kt, set)                                                        \
  _Pragma("unroll") for (int q_ = 0; q_ < 4; ++q_) {                           \
    const char* p_ = bbase + (size_t)((q_ >> 1) * 32 + (q_ & 1) * 16) * 1024 + \
                     (size_t)(kt) * 128;                                       \
    const i32x4 lo_ = *(const i32x4*)p_;                                       \
    const i32x4 hi_ = *(const i32x4*)(p_ + 16);                                \
    breg[set][q_] = (i32x8){lo_[0], lo_[1], lo_[2], lo_[3],                    \
                            hi_[0], hi_[1], hi_[2], hi_[3]};                   \
  }

#define MFMAQ(mq, nq, bset)                                                    \
  _Pragma("unroll") for (int mf_ = 0; mf_ < 4; ++mf_)                          \
  _Pragma("unroll") for (int nf_ = 0; nf_ < 2; ++nf_)                          \
    acc[(mq) * 4 + mf_][(nq) * 2 + nf_] =                                      \
        __builtin_amdgcn_mfma_scale_f32_16x16x128_f8f6f4(                      \
            areg[mf_], bset[(nq) * 2 + nf_],                                   \
            acc[(mq) * 4 + mf_][(nq) * 2 + nf_], 0, 0, 0, SCL, 0, SCL);

__global__ __launch_bounds__(512, 1)
void lse_gemm(const unsigned char* __restrict__ hf8,
              const unsigned char* __restrict__ wf8,
              const float* __restrict__ bias,
              float* __restrict__ ps) {
  __shared__ __align__(16) char smem[69632];  // A dbuf 2x32KB; epilogue 256x68 f32

  const int bid = (int)blockIdx.x;
  const int logical = (bid & 7) * (NBLK / 8) + (bid >> 3);  // T1 XCD chunking
  const int colt = logical >> 3;           // 0..511
  const int m0 = (logical & 7) * BM;
  const int v0 = colt * BN;

  const int tid = threadIdx.x;
  const int w = tid >> 6, lane = tid & 63;
  const int wm = w >> 2, wn = w & 3;       // 2 x 4 waves, each 128x64 output
  const int l15 = lane & 15, l16g = lane >> 4;
  const int swz = (lane & 7) << 4;         // read-side XOR (row&7 == lane&7)

  // A staging source: granule-permuted + swizzled so LDS granule q' of row r
  // holds global granule F(q' ^ (r&7)), F = {0,2,4,6,1,3,5,7}.
  const int x_ = (tid & 7) ^ ((tid >> 3) & 7);
  const int scolb = ((x_ < 4) ? (x_ * 2) : ((x_ & 3) * 2 + 1)) << 4;
  const char* habase = (const char*)hf8 + (size_t)(m0 + (tid >> 3)) * D_DIM + scolb;
  // B register-load base: lane (l&15) -> col, (l>>4) -> 32B k-granule pair
  const char* bbase = (const char*)wf8 + (size_t)(v0 + wn * 64 + l15) * D_DIM
                      + l16g * 32;

  f32x4 acc[8][4];
  const f32x4 zero = {0.f, 0.f, 0.f, 0.f};
#pragma unroll
  for (int i = 0; i < 8; ++i)
#pragma unroll
    for (int j = 0; j < 4; ++j) acc[i][j] = zero;

  i32x8 areg[4], breg[2][4];

  // ---- prologue: stage A(0), load B(0); order pinned [A-DMA][B-regs] ----
  STAGE_A(0, 0);
  SCHB();
  LOAD_B(0, 0);
  SCHB();

  // ---- main loop: 1 K-tile per iter, one barrier per iter ----
#pragma unroll
  for (int t = 0; t < K_TILES; ++t) {
    const int buf = t & 1;
    VM8();                 // A(t) DMA landed (4 oldest of [A:4][B:8])
    BAR();                 // all waves' A(t) visible; prev-tile readers done
    if (t < K_TILES - 1) {
      STAGE_A(t + 1, buf ^ 1);
      SCHB();
      LOAD_B(t + 1, buf ^ 1);
      SCHB();
    }
    READ_A(0, buf);
    SP1(); MFMAQ(0, 0, breg[buf]); MFMAQ(0, 1, breg[buf]); SP0();
    READ_A(1, buf);
    SP1(); MFMAQ(1, 0, breg[buf]); MFMAQ(1, 1, breg[buf]); SP0();
  }
  __syncthreads();

  // ---- epilogue: per-row sum(exp(x+bias)) over this tile's 256 cols ----
  float* red = (float*)smem;               // [256][68] f32 (pad)
  float bv[4];
#pragma unroll
  for (int q = 0; q < 4; ++q)              // q = nq*2+nf
    bv[q] = bias[v0 + wn * 64 + (q >> 1) * 32 + (q & 1) * 16 + l15];
#pragma unroll
  for (int mi = 0; mi < 8; ++mi) {
#pragma unroll
    for (int r = 0; r < 4; ++r) {
      const float v = __expf(acc[mi][0][r] + bv[0]) + __expf(acc[mi][1][r] + bv[1]) +
                      __expf(acc[mi][2][r] + bv[2]) + __expf(acc[mi][3][r] + bv[3]);
      const int row = wm * 128 + (mi >> 2) * 64 + (mi & 3) * 16 + l16g * 4 + r;
      red[row * 68 + wn * 16 + l15] = v;
    }
  }
  __syncthreads();
  {
    const int row = tid >> 1, h = tid & 1;
    const float* rr = &red[row * 68 + h * 32];
    f32x4 s4 = *(const f32x4*)rr;
#pragma unroll
    for (int i = 1; i < 8; ++i) s4 += *(const f32x4*)(rr + i * 4);
    float s = s4[0] + s4[1] + s4[2] + s4[3];
    s += __shfl_xor(s, 1);
    if (h == 0) ps[(size_t)(m0 + row) * COL_TILES + colt] = s;
  }
}

// ---------------- per-row finalize: sum partials -> lse, target logit, ce ----
__global__ __launch_bounds__(256)
void row_finalize(const float* __restrict__ ps,
                  const float* __restrict__ hidden, const float* __restrict__ weight,
                  const float* __restrict__ bias, const int* __restrict__ labels,
                  float* __restrict__ ce) {
  __shared__ float ss[4], sd[4];
  const int row = blockIdx.x;
  const int t = threadIdx.x, lane = t & 63, w = t >> 6;

  float s = 0.f;
#pragma unroll
  for (int i = 0; i < COL_TILES / 256; ++i)
    s += ps[(size_t)row * COL_TILES + t + i * 256];

  const int lbl = labels[row];
  const bool valid = (lbl != IGNORE_INDEX);
  float dot = 0.f;
  if (valid) {
    const float4 h4 = *(const float4*)&hidden[(size_t)row * D_DIM + t * 4];
    const float4 w4 = *(const float4*)&weight[(size_t)lbl * D_DIM + t * 4];
    dot = h4.x * w4.x + h4.y * w4.y + h4.z * w4.z + h4.w * w4.w;
  }
#pragma unroll
  for (int msk = 1; msk < 64; msk <<= 1) {
    s += __shfl_xor(s, msk);
    dot += __shfl_xor(dot, msk);
  }
  if (lane == 0) { ss[w] = s; sd[w] = dot; }
  __syncthreads();
  if (t == 0) {
    const float S = ss[0] + ss[1] + ss[2] + ss[3];
    const float d = sd[0] + sd[1] + sd[2] + sd[3];
    ce[row] = valid ? (logf(S + 1e-10f) - (d + bias[lbl])) : 0.f;
  }
}

// ---------------- final scalar reduce ----------------
__global__ __launch_bounds__(256)
void final_reduce(const float* __restrict__ ce, const int* __restrict__ labels,
                  float* __restrict__ out) {
  __shared__ float ssum[4];
  __shared__ int scnt[4];
  const int t = threadIdx.x, lane = t & 63, w = t >> 6;
  float sum = 0.f; int cnt = 0;
  for (int i = t; i < N_ROWS; i += 256) {
    sum += ce[i];
    cnt += (labels[i] != IGNORE_INDEX) ? 1 : 0;
  }
#pragma unroll
  for (int msk = 1; msk < 64; msk <<= 1) {
    sum += __shfl_xor(sum, msk);
    cnt += __shfl_xor(cnt, msk);
  }
  if (lane == 0) { ssum[w] = sum; scnt[w] = cnt; }
  __syncthreads();
  if (t == 0) {
    const float S = ssum[0] + ssum[1] + ssum[2] + ssum[3];
    const int C = scnt[0] + scnt[1] + scnt[2] + scnt[3];
    out[0] = S / fmaxf((float)C, 1.f);
  }
}

extern "C" void kernel_launch(void* const* d_in, const int* in_sizes, int n_in,
                              void* d_out, int out_size, void* d_ws, size_t ws_size,
                              hipStream_t stream) {
  const float* hidden = (const float*)d_in[0];
  const float* weight = (const float*)d_in[1];
  const float* bias   = (const float*)d_in[2];
  const int*   labels = (const int*)d_in[3];
  float* out = (float*)d_out;

  const size_t WF8_B = (size_t)V_DIM * D_DIM;              // 128 MB
  const size_t HF8_B = (size_t)N_ROWS * D_DIM;             // 2 MB
  const size_t PS_B  = (size_t)N_ROWS * COL_TILES * 4;     // 4 MB
  const size_t CE_B  = (size_t)N_ROWS * 4;
  if (ws_size < WF8_B + HF8_B + PS_B + CE_B) return;

  char* ws = (char*)d_ws;
  unsigned char* wf8 = (unsigned char*)ws;
  unsigned char* hf8 = (unsigned char*)(ws + WF8_B);
  float* ps = (float*)(ws + WF8_B + HF8_B);
  float* ce = (float*)(ws + WF8_B + HF8_B + PS_B);

  cvt_fp8<<<(int)((size_t)V_DIM * D_DIM / 4096), 256, 0, stream>>>(weight, wf8);
  cvt_fp8<<<(int)((size_t)N_ROWS * D_DIM / 4096), 256, 0, stream>>>(hidden, hf8);
  lse_gemm<<<NBLK, 512, 0, stream>>>(hf8, wf8, bias, ps);
  row_finalize<<<N_ROWS, 256, 0, stream>>>(ps, hidden, weight, bias, labels, ce);
  final_reduce<<<1, 256, 0, stream>>>(ce, labels, out);
}

// Round 6
// 524.583 us; speedup vs baseline: 1.1750x; 1.1750x over previous
//
#include <hip/hip_runtime.h>

#define IGNORE_INDEX (-100)

constexpr int N_ROWS = 2048;
constexpr int D_DIM  = 1024;
constexpr int V_DIM  = 131072;
constexpr int BM = 256, BN = 256, BK = 128;
constexpr int ROW_TILES = N_ROWS / BM;        // 8
constexpr int COL_TILES = V_DIM / BN;         // 512
constexpr int NBLK = ROW_TILES * COL_TILES;   // 4096
constexpr int K_TILES = D_DIM / BK;           // 8

typedef __attribute__((ext_vector_type(4))) float f32x4;
typedef __attribute__((ext_vector_type(4))) int   i32x4;
typedef __attribute__((ext_vector_type(8))) int   i32x8;

// E8M0 scale 121 = 2^-6 in every byte: uniform -> lane/byte-select layout-proof.
#define SCL 0x79797979
#define PRESCALE 64.0f

// ---------------- f32 -> fp8 e4m3 (x64 pre-scale), 16 elems/thread ----------
__global__ __launch_bounds__(256)
void cvt_fp8(const float* __restrict__ src, unsigned char* __restrict__ dst) {
  const size_t i = ((size_t)blockIdx.x * 256 + (size_t)threadIdx.x) * 16;
  i32x4 o;
#pragma unroll
  for (int q = 0; q < 4; ++q) {
    const float4 f = *(const float4*)&src[i + q * 4];
    int w = 0;
    w = __builtin_amdgcn_cvt_pk_fp8_f32(f.x * PRESCALE, f.y * PRESCALE, w, false);
    w = __builtin_amdgcn_cvt_pk_fp8_f32(f.z * PRESCALE, f.w * PRESCALE, w, true);
    o[q] = w;
  }
  *(i32x4*)&dst[i] = o;
}

// ---------------- 256x256 MX-fp8 GEMM + partial row exp-sum ----------------
// A (hidden) staged in LDS (shared x4 by wn-waves); B (weight) loaded straight
// from global into registers. One barrier per K-tile; vmcnt(8) drains exactly
// the A-DMA. A-fragments STREAMED 2-deep (ar[2]) to stay under the 128-VGPR
// budget (acc=128 AGPR; 512-thr block caps unified regs at 256/wave).
#define BAR() __builtin_amdgcn_s_barrier()
#define SP1() __builtin_amdgcn_s_setprio(1)
#define SP0() __builtin_amdgcn_s_setprio(0)
#define SCHB() __builtin_amdgcn_sched_barrier(0)
#define VM8() asm volatile("s_waitcnt vmcnt(8)" ::: "memory")

// stage one 256x128 fp8 A-tile: 4 x global_load_lds(16B)/thread
#define STAGE_A(kt, buf)                                                       \
  {                                                                            \
    _Pragma("unroll") for (int j2_ = 0; j2_ < 4; ++j2_) {                      \
      const char* g_ = habase + (size_t)(j2_ * 64) * 1024 + (size_t)(kt) * 128;\
      __builtin_amdgcn_global_load_lds(                                        \
          (const __attribute__((address_space(1))) unsigned int*)g_,           \
          (__attribute__((address_space(3))) unsigned int*)(smem +             \
              (buf) * 32768 + j2_ * 8192 + (w << 10)),                         \
          16, 0, 0);                                                           \
    }                                                                          \
  }

// read ONE A-frag (16 rows x K=128) from LDS into dst (i32x8)
#define READ_FRAG(f, buf, dst)                                                 \
  {                                                                            \
    const char* p_ = smem + (buf) * 32768 + (wm * 128 + (f) * 16 + l15) * 128; \
    const i32x4 lo_ = *(const i32x4*)(p_ + ((l16g * 16) ^ swz));               \
    const i32x4 hi_ = *(const i32x4*)(p_ + ((64 + l16g * 16) ^ swz));          \
    dst = (i32x8){lo_[0], lo_[1], lo_[2], lo_[3],                              \
                  hi_[0], hi_[1], hi_[2], hi_[3]};                             \
  }

// load 4 B-frags (whole wave-column, one K-tile) global -> regs
#define LOAD_B(kt, set)                                                        \
  _Pragma("unroll") for (int q_ = 0; q_ < 4; ++q_) {                           \
    const char* p_ = bbase + (size_t)((q_ >> 1) * 32 + (q_ & 1) * 16) * 1024 + \
                     (size_t)(kt) * 128;                                       \
    const i32x4 lo_ = *(const i32x4*)p_;                                       \
    const i32x4 hi_ = *(const i32x4*)(p_ + 16);                                \
    breg[set][q_] = (i32x8){lo_[0], lo_[1], lo_[2], lo_[3],                    \
                            hi_[0], hi_[1], hi_[2], hi_[3]};                   \
  }

__global__ __launch_bounds__(512, 1)
void lse_gemm(const unsigned char* __restrict__ hf8,
              const unsigned char* __restrict__ wf8,
              const float* __restrict__ bias,
              float* __restrict__ ps) {
  __shared__ __align__(16) char smem[69632];  // A dbuf 2x32KB; epilogue 256x68 f32

  const int bid = (int)blockIdx.x;
  const int logical = (bid & 7) * (NBLK / 8) + (bid >> 3);  // T1 XCD chunking
  const int colt = logical >> 3;           // 0..511
  const int m0 = (logical & 7) * BM;
  const int v0 = colt * BN;

  const int tid = threadIdx.x;
  const int w = tid >> 6, lane = tid & 63;
  const int wm = w >> 2, wn = w & 3;       // 2 x 4 waves, each 128x64 output
  const int l15 = lane & 15, l16g = lane >> 4;
  const int swz = (lane & 7) << 4;         // read-side XOR (row&7 == lane&7)

  // A staging source: granule-permuted + swizzled so LDS granule q' of row r
  // holds global granule F(q' ^ (r&7)), F = {0,2,4,6,1,3,5,7}.
  const int x_ = (tid & 7) ^ ((tid >> 3) & 7);
  const int scolb = ((x_ < 4) ? (x_ * 2) : ((x_ & 3) * 2 + 1)) << 4;
  const char* habase = (const char*)hf8 + (size_t)(m0 + (tid >> 3)) * D_DIM + scolb;
  // B register-load base: lane (l&15) -> col, (l>>4) -> 32B k-granule pair
  const char* bbase = (const char*)wf8 + (size_t)(v0 + wn * 64 + l15) * D_DIM
                      + l16g * 32;

  f32x4 acc[8][4];
  const f32x4 zero = {0.f, 0.f, 0.f, 0.f};
#pragma unroll
  for (int i = 0; i < 8; ++i)
#pragma unroll
    for (int j = 0; j < 4; ++j) acc[i][j] = zero;

  i32x8 ar[2], breg[2][4];

  // ---- prologue: stage A(0), load B(0); order pinned [A-DMA][B-regs] ----
  STAGE_A(0, 0);
  SCHB();
  LOAD_B(0, 0);
  SCHB();

  // ---- main loop: 1 K-tile per iter, one barrier per iter ----
#pragma unroll
  for (int t = 0; t < K_TILES; ++t) {
    const int buf = t & 1;
    VM8();                 // A(t) DMA landed (4 oldest of [A:4][B:8])
    BAR();                 // all waves' A(t) visible; prev-tile readers done
    if (t < K_TILES - 1) {
      STAGE_A(t + 1, buf ^ 1);
      SCHB();
      LOAD_B(t + 1, buf ^ 1);
      SCHB();
    }
    // ---- stream 8 A-frags, 2-deep; 4 MFMAs per frag ----
    READ_FRAG(0, buf, ar[0]);
#pragma unroll
    for (int f = 0; f < 8; ++f) {
      if (f < 7) READ_FRAG(f + 1, buf, ar[(f + 1) & 1]);
      SP1();
#pragma unroll
      for (int q = 0; q < 4; ++q)
        acc[f][q] = __builtin_amdgcn_mfma_scale_f32_16x16x128_f8f6f4(
            ar[f & 1], breg[buf][q], acc[f][q], 0, 0, 0, SCL, 0, SCL);
      SP0();
    }
  }
  __syncthreads();

  // ---- epilogue: per-row sum(exp(x+bias)) over this tile's 256 cols ----
  float* red = (float*)smem;               // [256][68] f32 (pad)
  float bv[4];
#pragma unroll
  for (int q = 0; q < 4; ++q)              // q = nq*2+nf
    bv[q] = bias[v0 + wn * 64 + (q >> 1) * 32 + (q & 1) * 16 + l15];
#pragma unroll
  for (int mi = 0; mi < 8; ++mi) {
#pragma unroll
    for (int r = 0; r < 4; ++r) {
      const float v = __expf(acc[mi][0][r] + bv[0]) + __expf(acc[mi][1][r] + bv[1]) +
                      __expf(acc[mi][2][r] + bv[2]) + __expf(acc[mi][3][r] + bv[3]);
      const int row = wm * 128 + mi * 16 + l16g * 4 + r;
      red[row * 68 + wn * 16 + l15] = v;
    }
  }
  __syncthreads();
  {
    const int row = tid >> 1, h = tid & 1;
    const float* rr = &red[row * 68 + h * 32];
    f32x4 s4 = *(const f32x4*)rr;
#pragma unroll
    for (int i = 1; i < 8; ++i) s4 += *(const f32x4*)(rr + i * 4);
    float s = s4[0] + s4[1] + s4[2] + s4[3];
    s += __shfl_xor(s, 1);
    if (h == 0) ps[(size_t)(m0 + row) * COL_TILES + colt] = s;
  }
}

// ---------------- per-row finalize: sum partials -> lse, target logit, ce ----
__global__ __launch_bounds__(256)
void row_finalize(const float* __restrict__ ps,
                  const float* __restrict__ hidden, const float* __restrict__ weight,
                  const float* __restrict__ bias, const int* __restrict__ labels,
                  float* __restrict__ ce) {
  __shared__ float ss[4], sd[4];
  const int row = blockIdx.x;
  const int t = threadIdx.x, lane = t & 63, w = t >> 6;

  float s = 0.f;
#pragma unroll
  for (int i = 0; i < COL_TILES / 256; ++i)
    s += ps[(size_t)row * COL_TILES + t + i * 256];

  const int lbl = labels[row];
  const bool valid = (lbl != IGNORE_INDEX);
  float dot = 0.f;
  if (valid) {
    const float4 h4 = *(const float4*)&hidden[(size_t)row * D_DIM + t * 4];
    const float4 w4 = *(const float4*)&weight[(size_t)lbl * D_DIM + t * 4];
    dot = h4.x * w4.x + h4.y * w4.y + h4.z * w4.z + h4.w * w4.w;
  }
#pragma unroll
  for (int msk = 1; msk < 64; msk <<= 1) {
    s += __shfl_xor(s, msk);
    dot += __shfl_xor(dot, msk);
  }
  if (lane == 0) { ss[w] = s; sd[w] = dot; }
  __syncthreads();
  if (t == 0) {
    const float S = ss[0] + ss[1] + ss[2] + ss[3];
    const float d = sd[0] + sd[1] + sd[2] + sd[3];
    ce[row] = valid ? (logf(S + 1e-10f) - (d + bias[lbl])) : 0.f;
  }
}

// ---------------- final scalar reduce ----------------
__global__ __launch_bounds__(256)
void final_reduce(const float* __restrict__ ce, const int* __restrict__ labels,
                  float* __restrict__ out) {
  __shared__ float ssum[4];
  __shared__ int scnt[4];
  const int t = threadIdx.x, lane = t & 63, w = t >> 6;
  float sum = 0.f; int cnt = 0;
  for (int i = t; i < N_ROWS; i += 256) {
    sum += ce[i];
    cnt += (labels[i] != IGNORE_INDEX) ? 1 : 0;
  }
#pragma unroll
  for (int msk = 1; msk < 64; msk <<= 1) {
    sum += __shfl_xor(sum, msk);
    cnt += __shfl_xor(cnt, msk);
  }
  if (lane == 0) { ssum[w] = sum; scnt[w] = cnt; }
  __syncthreads();
  if (t == 0) {
    const float S = ssum[0] + ssum[1] + ssum[2] + ssum[3];
    const int C = scnt[0] + scnt[1] + scnt[2] + scnt[3];
    out[0] = S / fmaxf((float)C, 1.f);
  }
}

extern "C" void kernel_launch(void* const* d_in, const int* in_sizes, int n_in,
                              void* d_out, int out_size, void* d_ws, size_t ws_size,
                              hipStream_t stream) {
  const float* hidden = (const float*)d_in[0];
  const float* weight = (const float*)d_in[1];
  const float* bias   = (const float*)d_in[2];
  const int*   labels = (const int*)d_in[3];
  float* out = (float*)d_out;

  const size_t WF8_B = (size_t)V_DIM * D_DIM;              // 128 MB
  const size_t HF8_B = (size_t)N_ROWS * D_DIM;             // 2 MB
  const size_t PS_B  = (size_t)N_ROWS * COL_TILES * 4;     // 4 MB
  const size_t CE_B  = (size_t)N_ROWS * 4;
  if (ws_size < WF8_B + HF8_B + PS_B + CE_B) return;

  char* ws = (char*)d_ws;
  unsigned char* wf8 = (unsigned char*)ws;
  unsigned char* hf8 = (unsigned char*)(ws + WF8_B);
  float* ps = (float*)(ws + WF8_B + HF8_B);
  float* ce = (float*)(ws + WF8_B + HF8_B + PS_B);

  cvt_fp8<<<(int)((size_t)V_DIM * D_DIM / 4096), 256, 0, stream>>>(weight, wf8);
  cvt_fp8<<<(int)((size_t)N_ROWS * D_DIM / 4096), 256, 0, stream>>>(hidden, hf8);
  lse_gemm<<<NBLK, 512, 0, stream>>>(hf8, wf8, bias, ps);
  row_finalize<<<N_ROWS, 256, 0, stream>>>(ps, hidden, weight, bias, labels, ce);
  final_reduce<<<1, 256, 0, stream>>>(ce, labels, out);
}

// Round 7
// 376.200 us; speedup vs baseline: 1.6385x; 1.3944x over previous
//
#include <hip/hip_runtime.h>

#define IGNORE_INDEX (-100)

constexpr int N_ROWS = 2048;
constexpr int D_DIM  = 1024;
constexpr int V_DIM  = 131072;
constexpr int BM = 256, BN = 256, BK = 128;
constexpr int ROW_TILES = N_ROWS / BM;        // 8
constexpr int COL_TILES = V_DIM / BN;         // 512
constexpr int NBLK = ROW_TILES * COL_TILES;   // 4096
constexpr int K_TILES = D_DIM / BK;           // 8

typedef __attribute__((ext_vector_type(4))) float f32x4;
typedef __attribute__((ext_vector_type(4))) int   i32x4;
typedef __attribute__((ext_vector_type(8))) int   i32x8;

// E8M0 scale 121 = 2^-6 in every byte: uniform -> lane/byte-select layout-proof.
#define SCL 0x79797979
#define PRESCALE 64.0f

// ---------------- f32 -> fp8 e4m3 (x64 pre-scale), 16 elems/thread ----------
__global__ __launch_bounds__(256)
void cvt_fp8(const float* __restrict__ src, unsigned char* __restrict__ dst) {
  const size_t i = ((size_t)blockIdx.x * 256 + (size_t)threadIdx.x) * 16;
  i32x4 o;
#pragma unroll
  for (int q = 0; q < 4; ++q) {
    const float4 f = *(const float4*)&src[i + q * 4];
    int w = 0;
    w = __builtin_amdgcn_cvt_pk_fp8_f32(f.x * PRESCALE, f.y * PRESCALE, w, false);
    w = __builtin_amdgcn_cvt_pk_fp8_f32(f.z * PRESCALE, f.w * PRESCALE, w, true);
    o[q] = w;
  }
  *(i32x4*)&dst[i] = o;
}

// ---------------- 256x256 MX-fp8 GEMM + partial row exp-sum ----------------
// Both A (hidden) and B (weight) staged in LDS via coalesced global_load_lds,
// granule-permuted so reads use the proven conflict-free pattern. ONE barrier
// + ONE vmcnt(0) per K-tile: stages for t+1 issue right after the barrier and
// have the whole compute phase (~2300 cyc LDS-bound) to land. B-frags read
// once/tile into 32 regs (x8 reuse); A-frags streamed 2-deep.
#define BAR() __builtin_amdgcn_s_barrier()
#define SP1() __builtin_amdgcn_s_setprio(1)
#define SP0() __builtin_amdgcn_s_setprio(0)
#define SCHB() __builtin_amdgcn_sched_barrier(0)
#define VM0() asm volatile("s_waitcnt vmcnt(0)" ::: "memory")

// stage one 256x128 fp8 tile: 4 x global_load_lds(16B)/thread, coalesced
#define STAGE(gbase, ldsoff, kt, buf)                                          \
  {                                                                            \
    _Pragma("unroll") for (int j2_ = 0; j2_ < 4; ++j2_) {                      \
      const char* g_ = (gbase) + (size_t)(j2_ * 64) * 1024 + (size_t)(kt) * 128;\
      __builtin_amdgcn_global_load_lds(                                        \
          (const __attribute__((address_space(1))) unsigned int*)g_,           \
          (__attribute__((address_space(3))) unsigned int*)(smem + (ldsoff) +  \
              (buf) * 65536 + j2_ * 8192 + (w << 10)),                         \
          16, 0, 0);                                                           \
    }                                                                          \
  }

// read ONE frag (16 rows x K=128) from LDS into dst (i32x8); conflict-free
#define READ_FRAG(ldsoff, rowbase, dst)                                        \
  {                                                                            \
    const char* p_ = smem + (ldsoff) + ((rowbase) + l15) * 128;                \
    const i32x4 lo_ = *(const i32x4*)(p_ + ((l16g * 16) ^ swz));               \
    const i32x4 hi_ = *(const i32x4*)(p_ + ((64 + l16g * 16) ^ swz));          \
    dst = (i32x8){lo_[0], lo_[1], lo_[2], lo_[3],                              \
                  hi_[0], hi_[1], hi_[2], hi_[3]};                             \
  }

__global__ __launch_bounds__(512, 1)
void lse_gemm(const unsigned char* __restrict__ hf8,
              const unsigned char* __restrict__ wf8,
              const float* __restrict__ bias,
              float* __restrict__ ps) {
  __shared__ __align__(16) char smem[131072];  // dbuf x (A 32KB | B 32KB)

  const int bid = (int)blockIdx.x;
  const int logical = (bid & 7) * (NBLK / 8) + (bid >> 3);  // T1 XCD chunking
  const int colt = logical >> 3;           // 0..511
  const int m0 = (logical & 7) * BM;
  const int v0 = colt * BN;

  const int tid = threadIdx.x;
  const int w = tid >> 6, lane = tid & 63;
  const int wm = w >> 2, wn = w & 3;       // 2 x 4 waves, each 128x64 output
  const int l15 = lane & 15, l16g = lane >> 4;
  const int swz = (lane & 7) << 4;         // read-side XOR (row&7 == lane&7)

  // staging source: granule-permuted + swizzled so LDS granule q' of row r
  // holds global granule F(q' ^ (r&7)), F = {0,2,4,6,1,3,5,7}.
  const int x_ = (tid & 7) ^ ((tid >> 3) & 7);
  const int scolb = ((x_ < 4) ? (x_ * 2) : ((x_ & 3) * 2 + 1)) << 4;
  const char* habase = (const char*)hf8 + (size_t)(m0 + (tid >> 3)) * D_DIM + scolb;
  const char* wbase  = (const char*)wf8 + (size_t)(v0 + (tid >> 3)) * D_DIM + scolb;

  f32x4 acc[8][4];
  const f32x4 zero = {0.f, 0.f, 0.f, 0.f};
#pragma unroll
  for (int i = 0; i < 8; ++i)
#pragma unroll
    for (int j = 0; j < 4; ++j) acc[i][j] = zero;

  i32x8 ar[2], breg[4];

  // ---- prologue: stage tile 0 into buf0 ----
  STAGE(habase, 0, 0, 0);
  STAGE(wbase, 32768, 0, 0);
  SCHB();

  // ---- main loop: 1 K-tile per iter; ONE vmcnt(0)+barrier per iter ----
#pragma unroll
  for (int t = 0; t < K_TILES; ++t) {
    const int buf = t & 1;
    VM0();                 // tile-t stages landed (issued a full phase ago)
    BAR();                 // all waves' stores visible; prev readers done
    if (t < K_TILES - 1) {
      STAGE(habase, 0, t + 1, buf ^ 1);
      STAGE(wbase, 32768, t + 1, buf ^ 1);
      SCHB();
    }
    // ---- B-frags once into regs (x8 reuse) ----
#pragma unroll
    for (int q = 0; q < 4; ++q)
      READ_FRAG(buf * 65536 + 32768, wn * 64 + (q >> 1) * 32 + (q & 1) * 16,
                breg[q]);
    // ---- stream 8 A-frags, 2-deep; 4 MFMAs per frag ----
    READ_FRAG(buf * 65536, wm * 128, ar[0]);
#pragma unroll
    for (int f = 0; f < 8; ++f) {
      if (f < 7) READ_FRAG(buf * 65536, wm * 128 + (f + 1) * 16, ar[(f + 1) & 1]);
      SP1();
#pragma unroll
      for (int q = 0; q < 4; ++q)
        acc[f][q] = __builtin_amdgcn_mfma_scale_f32_16x16x128_f8f6f4(
            ar[f & 1], breg[q], acc[f][q], 0, 0, 0, SCL, 0, SCL);
      SP0();
    }
  }
  __syncthreads();

  // ---- epilogue: per-row sum(exp(x+bias)) over this tile's 256 cols ----
  float* red = (float*)smem;               // [256][68] f32 (pad)
  float bv[4];
#pragma unroll
  for (int q = 0; q < 4; ++q)              // q = nq*2+nf
    bv[q] = bias[v0 + wn * 64 + (q >> 1) * 32 + (q & 1) * 16 + l15];
#pragma unroll
  for (int mi = 0; mi < 8; ++mi) {
#pragma unroll
    for (int r = 0; r < 4; ++r) {
      const float v = __expf(acc[mi][0][r] + bv[0]) + __expf(acc[mi][1][r] + bv[1]) +
                      __expf(acc[mi][2][r] + bv[2]) + __expf(acc[mi][3][r] + bv[3]);
      const int row = wm * 128 + mi * 16 + l16g * 4 + r;
      red[row * 68 + wn * 16 + l15] = v;
    }
  }
  __syncthreads();
  {
    const int row = tid >> 1, h = tid & 1;
    const float* rr = &red[row * 68 + h * 32];
    f32x4 s4 = *(const f32x4*)rr;
#pragma unroll
    for (int i = 1; i < 8; ++i) s4 += *(const f32x4*)(rr + i * 4);
    float s = s4[0] + s4[1] + s4[2] + s4[3];
    s += __shfl_xor(s, 1);
    if (h == 0) ps[(size_t)(m0 + row) * COL_TILES + colt] = s;
  }
}

// ---------------- per-row finalize: sum partials -> lse, target logit, ce ----
__global__ __launch_bounds__(256)
void row_finalize(const float* __restrict__ ps,
                  const float* __restrict__ hidden, const float* __restrict__ weight,
                  const float* __restrict__ bias, const int* __restrict__ labels,
                  float* __restrict__ ce) {
  __shared__ float ss[4], sd[4];
  const int row = blockIdx.x;
  const int t = threadIdx.x, lane = t & 63, w = t >> 6;

  float s = 0.f;
#pragma unroll
  for (int i = 0; i < COL_TILES / 256; ++i)
    s += ps[(size_t)row * COL_TILES + t + i * 256];

  const int lbl = labels[row];
  const bool valid = (lbl != IGNORE_INDEX);
  float dot = 0.f;
  if (valid) {
    const float4 h4 = *(const float4*)&hidden[(size_t)row * D_DIM + t * 4];
    const float4 w4 = *(const float4*)&weight[(size_t)lbl * D_DIM + t * 4];
    dot = h4.x * w4.x + h4.y * w4.y + h4.z * w4.z + h4.w * w4.w;
  }
#pragma unroll
  for (int msk = 1; msk < 64; msk <<= 1) {
    s += __shfl_xor(s, msk);
    dot += __shfl_xor(dot, msk);
  }
  if (lane == 0) { ss[w] = s; sd[w] = dot; }
  __syncthreads();
  if (t == 0) {
    const float S = ss[0] + ss[1] + ss[2] + ss[3];
    const float d = sd[0] + sd[1] + sd[2] + sd[3];
    ce[row] = valid ? (logf(S + 1e-10f) - (d + bias[lbl])) : 0.f;
  }
}

// ---------------- final scalar reduce ----------------
__global__ __launch_bounds__(256)
void final_reduce(const float* __restrict__ ce, const int* __restrict__ labels,
                  float* __restrict__ out) {
  __shared__ float ssum[4];
  __shared__ int scnt[4];
  const int t = threadIdx.x, lane = t & 63, w = t >> 6;
  float sum = 0.f; int cnt = 0;
  for (int i = t; i < N_ROWS; i += 256) {
    sum += ce[i];
    cnt += (labels[i] != IGNORE_INDEX) ? 1 : 0;
  }
#pragma unroll
  for (int msk = 1; msk < 64; msk <<= 1) {
    sum += __shfl_xor(sum, msk);
    cnt += __shfl_xor(cnt, msk);
  }
  if (lane == 0) { ssum[w] = sum; scnt[w] = cnt; }
  __syncthreads();
  if (t == 0) {
    const float S = ssum[0] + ssum[1] + ssum[2] + ssum[3];
    const int C = scnt[0] + scnt[1] + scnt[2] + scnt[3];
    out[0] = S / fmaxf((float)C, 1.f);
  }
}

extern "C" void kernel_launch(void* const* d_in, const int* in_sizes, int n_in,
                              void* d_out, int out_size, void* d_ws, size_t ws_size,
                              hipStream_t stream) {
  const float* hidden = (const float*)d_in[0];
  const float* weight = (const float*)d_in[1];
  const float* bias   = (const float*)d_in[2];
  const int*   labels = (const int*)d_in[3];
  float* out = (float*)d_out;

  const size_t WF8_B = (size_t)V_DIM * D_DIM;              // 128 MB
  const size_t HF8_B = (size_t)N_ROWS * D_DIM;             // 2 MB
  const size_t PS_B  = (size_t)N_ROWS * COL_TILES * 4;     // 4 MB
  const size_t CE_B  = (size_t)N_ROWS * 4;
  if (ws_size < WF8_B + HF8_B + PS_B + CE_B) return;

  char* ws = (char*)d_ws;
  unsigned char* wf8 = (unsigned char*)ws;
  unsigned char* hf8 = (unsigned char*)(ws + WF8_B);
  float* ps = (float*)(ws + WF8_B + HF8_B);
  float* ce = (float*)(ws + WF8_B + HF8_B + PS_B);

  cvt_fp8<<<(int)((size_t)V_DIM * D_DIM / 4096), 256, 0, stream>>>(weight, wf8);
  cvt_fp8<<<(int)((size_t)N_ROWS * D_DIM / 4096), 256, 0, stream>>>(hidden, hf8);
  lse_gemm<<<NBLK, 512, 0, stream>>>(hf8, wf8, bias, ps);
  row_finalize<<<N_ROWS, 256, 0, stream>>>(ps, hidden, weight, bias, labels, ce);
  final_reduce<<<1, 256, 0, stream>>>(ce, labels, out);
}

// Round 8
// 312.805 us; speedup vs baseline: 1.9705x; 1.2027x over previous
//
#include <hip/hip_runtime.h>

#define IGNORE_INDEX (-100)

constexpr int N_ROWS = 2048;
constexpr int D_DIM  = 1024;
constexpr int V_DIM  = 131072;
constexpr int BM = 256, BN = 256, BK = 128;
constexpr int ROW_TILES = N_ROWS / BM;        // 8
constexpr int COL_TILES = V_DIM / BN;         // 512
constexpr int NBLK = ROW_TILES * COL_TILES;   // 4096
constexpr int K_TILES = D_DIM / BK;           // 8

typedef __attribute__((ext_vector_type(4))) float f32x4;
typedef __attribute__((ext_vector_type(4))) int   i32x4;
typedef __attribute__((ext_vector_type(8))) int   i32x8;

// Uniform E8M0 scales (every byte equal -> lane/byte-select layout-proof):
// hidden stored at prescale 1 (scale 2^0 = code 127), weight at prescale 64
// (scale 2^-6 = code 121). Product: 2^0 * 2^-6 * 64 = 1.
#define SCL_A 0x7F7F7F7Fu
#define SCL_B 0x79797979u

// ---------------- f32 -> fp4 e2m1 (software RNE to grid), 32 elems/thread ----
// e2m1 magnitudes: code 0..7 -> {0,0.5,1,1.5,2,3,4,6}; thresholds are midpoints.
__device__ __forceinline__ unsigned int f2fp4(float f) {
  const float a = fabsf(f);
  unsigned int c = (unsigned)(a >= 0.25f) + (unsigned)(a >= 0.75f) +
                   (unsigned)(a >= 1.25f) + (unsigned)(a >= 1.75f) +
                   (unsigned)(a >= 2.5f)  + (unsigned)(a >= 3.5f) +
                   (unsigned)(a >= 5.0f);
  return c | ((__float_as_uint(f) >> 31) << 3);
}

__global__ __launch_bounds__(256)
void cvt_fp4(const float* __restrict__ src, unsigned char* __restrict__ dst,
             float prescale) {
  const size_t i = ((size_t)blockIdx.x * 256 + (size_t)threadIdx.x) * 32;
  i32x4 o;
#pragma unroll
  for (int q = 0; q < 4; ++q) {        // 1 dword = 8 elems, low nibble first
    unsigned int wrd = 0;
#pragma unroll
    for (int e = 0; e < 8; e += 4) {
      const float4 f = *(const float4*)&src[i + q * 8 + e];
      wrd |= f2fp4(f.x * prescale) << ((e + 0) * 4);
      wrd |= f2fp4(f.y * prescale) << ((e + 1) * 4);
      wrd |= f2fp4(f.z * prescale) << ((e + 2) * 4);
      wrd |= f2fp4(f.w * prescale) << ((e + 3) * 4);
    }
    o[q] = (int)wrd;
  }
  *(i32x4*)&dst[i / 2] = o;
}

// ---------------- 256x256 MX-fp4 GEMM + partial row exp-sum ----------------
// Round-7 structure frozen; operands are fp4 -> 64 B rows. Swizzle rederived
// for 64B rows: read slot g' = g ^ ((row>>1)&3) (2-way banks = free); staging
// source applies the same involution, LDS dest linear tid*16 (rule 21).
#define BAR() __builtin_amdgcn_s_barrier()
#define SP1() __builtin_amdgcn_s_setprio(1)
#define SP0() __builtin_amdgcn_s_setprio(0)
#define SCHB() __builtin_amdgcn_sched_barrier(0)
#define VM0() asm volatile("s_waitcnt vmcnt(0)" ::: "memory")

// stage one 256x128-elem fp4 tile (16 KB): 2 x global_load_lds(16B)/thread
#define STAGE(gbase, ldsoff, kt, buf)                                          \
  {                                                                            \
    _Pragma("unroll") for (int j2_ = 0; j2_ < 2; ++j2_) {                      \
      const char* g_ = (gbase) + (size_t)j2_ * 65536 + (size_t)(kt) * 64;      \
      __builtin_amdgcn_global_load_lds(                                        \
          (const __attribute__((address_space(1))) unsigned int*)g_,           \
          (__attribute__((address_space(3))) unsigned int*)(smem + (ldsoff) +  \
              (buf) * 16384 + j2_ * 8192 + (tid << 4)),                        \
          16, 0, 0);                                                           \
    }                                                                          \
  }

// read ONE frag (16 rows x K=128 fp4 = 16 B/lane) from LDS; conflict-free
#define READ_FRAG(ldsoff, rowbase, dst)                                        \
  {                                                                            \
    const i32x4 d_ = *(const i32x4*)(smem + (ldsoff) +                         \
                                     ((rowbase) + l15) * 64 + gcol);           \
    dst = (i32x8){d_[0], d_[1], d_[2], d_[3], 0, 0, 0, 0};                     \
  }

__global__ __launch_bounds__(512, 1)
void lse_gemm(const unsigned char* __restrict__ hf4,
              const unsigned char* __restrict__ wf4,
              const float* __restrict__ bias,
              float* __restrict__ ps) {
  __shared__ __align__(16) char smem[69632];  // A dbuf 2x16K | B dbuf 2x16K; epi 256x68 f32

  const int bid = (int)blockIdx.x;
  const int logical = (bid & 7) * (NBLK / 8) + (bid >> 3);  // T1 XCD chunking
  const int colt = logical >> 3;           // 0..511
  const int m0 = (logical & 7) * BM;
  const int v0 = colt * BN;

  const int tid = threadIdx.x;
  const int w = tid >> 6, lane = tid & 63;
  (void)w;
  const int wm = (tid >> 6) >> 2, wn = (tid >> 6) & 3;  // 2x4 waves, 128x64 out
  const int l15 = lane & 15, l16g = lane >> 4;
  const int gcol = (l16g ^ ((l15 >> 1) & 3)) << 4;      // read-side swizzle

  // staging source: row r = tid>>2, granule slot g = tid&3 holds global
  // granule G = g ^ ((r>>1)&3) (same involution as read side).
  const int r_ = tid >> 2, g_ = tid & 3;
  const int G_ = g_ ^ ((r_ >> 1) & 3);
  const char* habase = (const char*)hf4 + (size_t)(m0 + r_) * 512 + G_ * 16;
  const char* wbase  = (const char*)wf4 + (size_t)(v0 + r_) * 512 + G_ * 16;

  f32x4 acc[8][4];
  const f32x4 zero = {0.f, 0.f, 0.f, 0.f};
#pragma unroll
  for (int i = 0; i < 8; ++i)
#pragma unroll
    for (int j = 0; j < 4; ++j) acc[i][j] = zero;

  i32x8 ar[2], breg[4];

  // ---- prologue: stage tile 0 into buf0 ----
  STAGE(habase, 0, 0, 0);
  STAGE(wbase, 32768, 0, 0);
  SCHB();

  // ---- main loop: 1 K-tile per iter; ONE vmcnt(0)+barrier per iter ----
#pragma unroll
  for (int t = 0; t < K_TILES; ++t) {
    const int buf = t & 1;
    VM0();                 // tile-t stages landed (issued a full phase ago)
    BAR();                 // all waves' stores visible; prev readers done
    if (t < K_TILES - 1) {
      STAGE(habase, 0, t + 1, buf ^ 1);
      STAGE(wbase, 32768, t + 1, buf ^ 1);
      SCHB();
    }
    // ---- B-frags once into regs (x8 reuse) ----
#pragma unroll
    for (int q = 0; q < 4; ++q)
      READ_FRAG(32768 + buf * 16384, wn * 64 + q * 16, breg[q]);
    // ---- stream 8 A-frags, 2-deep; 4 MFMAs per frag; fmt 4 = fp4 e2m1 ----
    READ_FRAG(buf * 16384, wm * 128, ar[0]);
#pragma unroll
    for (int f = 0; f < 8; ++f) {
      if (f < 7) READ_FRAG(buf * 16384, wm * 128 + (f + 1) * 16, ar[(f + 1) & 1]);
      SP1();
#pragma unroll
      for (int q = 0; q < 4; ++q)
        acc[f][q] = __builtin_amdgcn_mfma_scale_f32_16x16x128_f8f6f4(
            ar[f & 1], breg[q], acc[f][q], 4, 4, 0, SCL_A, 0, SCL_B);
      SP0();
    }
  }
  __syncthreads();

  // ---- epilogue: per-row sum(exp(x+bias)) over this tile's 256 cols ----
  float* red = (float*)smem;               // [256][68] f32 (pad)
  float bv[4];
#pragma unroll
  for (int q = 0; q < 4; ++q)
    bv[q] = bias[v0 + wn * 64 + q * 16 + l15];
#pragma unroll
  for (int mi = 0; mi < 8; ++mi) {
#pragma unroll
    for (int r = 0; r < 4; ++r) {
      const float v = __expf(acc[mi][0][r] + bv[0]) + __expf(acc[mi][1][r] + bv[1]) +
                      __expf(acc[mi][2][r] + bv[2]) + __expf(acc[mi][3][r] + bv[3]);
      const int row = wm * 128 + mi * 16 + l16g * 4 + r;
      red[row * 68 + wn * 16 + l15] = v;
    }
  }
  __syncthreads();
  {
    const int row = tid >> 1, h = tid & 1;
    const float* rr = &red[row * 68 + h * 32];
    f32x4 s4 = *(const f32x4*)rr;
#pragma unroll
    for (int i = 1; i < 8; ++i) s4 += *(const f32x4*)(rr + i * 4);
    float s = s4[0] + s4[1] + s4[2] + s4[3];
    s += __shfl_xor(s, 1);
    if (h == 0) ps[(size_t)(m0 + row) * COL_TILES + colt] = s;
  }
}

// ---------------- per-row finalize: sum partials -> lse, target logit, ce ----
__global__ __launch_bounds__(256)
void row_finalize(const float* __restrict__ ps,
                  const float* __restrict__ hidden, const float* __restrict__ weight,
                  const float* __restrict__ bias, const int* __restrict__ labels,
                  float* __restrict__ ce) {
  __shared__ float ss[4], sd[4];
  const int row = blockIdx.x;
  const int t = threadIdx.x, lane = t & 63, w = t >> 6;

  float s = 0.f;
#pragma unroll
  for (int i = 0; i < COL_TILES / 256; ++i)
    s += ps[(size_t)row * COL_TILES + t + i * 256];

  const int lbl = labels[row];
  const bool valid = (lbl != IGNORE_INDEX);
  float dot = 0.f;
  if (valid) {
    const float4 h4 = *(const float4*)&hidden[(size_t)row * D_DIM + t * 4];
    const float4 w4 = *(const float4*)&weight[(size_t)lbl * D_DIM + t * 4];
    dot = h4.x * w4.x + h4.y * w4.y + h4.z * w4.z + h4.w * w4.w;
  }
#pragma unroll
  for (int msk = 1; msk < 64; msk <<= 1) {
    s += __shfl_xor(s, msk);
    dot += __shfl_xor(dot, msk);
  }
  if (lane == 0) { ss[w] = s; sd[w] = dot; }
  __syncthreads();
  if (t == 0) {
    const float S = ss[0] + ss[1] + ss[2] + ss[3];
    const float d = sd[0] + sd[1] + sd[2] + sd[3];
    ce[row] = valid ? (logf(S + 1e-10f) - (d + bias[lbl])) : 0.f;
  }
}

// ---------------- final scalar reduce ----------------
__global__ __launch_bounds__(256)
void final_reduce(const float* __restrict__ ce, const int* __restrict__ labels,
                  float* __restrict__ out) {
  __shared__ float ssum[4];
  __shared__ int scnt[4];
  const int t = threadIdx.x, lane = t & 63, w = t >> 6;
  float sum = 0.f; int cnt = 0;
  for (int i = t; i < N_ROWS; i += 256) {
    sum += ce[i];
    cnt += (labels[i] != IGNORE_INDEX) ? 1 : 0;
  }
#pragma unroll
  for (int msk = 1; msk < 64; msk <<= 1) {
    sum += __shfl_xor(sum, msk);
    cnt += __shfl_xor(cnt, msk);
  }
  if (lane == 0) { ssum[w] = sum; scnt[w] = cnt; }
  __syncthreads();
  if (t == 0) {
    const float S = ssum[0] + ssum[1] + ssum[2] + ssum[3];
    const int C = scnt[0] + scnt[1] + scnt[2] + scnt[3];
    out[0] = S / fmaxf((float)C, 1.f);
  }
}

extern "C" void kernel_launch(void* const* d_in, const int* in_sizes, int n_in,
                              void* d_out, int out_size, void* d_ws, size_t ws_size,
                              hipStream_t stream) {
  const float* hidden = (const float*)d_in[0];
  const float* weight = (const float*)d_in[1];
  const float* bias   = (const float*)d_in[2];
  const int*   labels = (const int*)d_in[3];
  float* out = (float*)d_out;

  const size_t WF4_B = (size_t)V_DIM * D_DIM / 2;          // 64 MB
  const size_t HF4_B = (size_t)N_ROWS * D_DIM / 2;         // 1 MB
  const size_t PS_B  = (size_t)N_ROWS * COL_TILES * 4;     // 4 MB
  const size_t CE_B  = (size_t)N_ROWS * 4;
  if (ws_size < WF4_B + HF4_B + PS_B + CE_B) return;

  char* ws = (char*)d_ws;
  unsigned char* wf4 = (unsigned char*)ws;
  unsigned char* hf4 = (unsigned char*)(ws + WF4_B);
  float* ps = (float*)(ws + WF4_B + HF4_B);
  float* ce = (float*)(ws + WF4_B + HF4_B + PS_B);

  cvt_fp4<<<(int)((size_t)V_DIM * D_DIM / 8192), 256, 0, stream>>>(weight, wf4, 64.0f);
  cvt_fp4<<<(int)((size_t)N_ROWS * D_DIM / 8192), 256, 0, stream>>>(hidden, hf4, 1.0f);
  lse_gemm<<<NBLK, 512, 0, stream>>>(hf4, wf4, bias, ps);
  row_finalize<<<N_ROWS, 256, 0, stream>>>(ps, hidden, weight, bias, labels, ce);
  final_reduce<<<1, 256, 0, stream>>>(ce, labels, out);
}